// Round 1
// baseline (530.269 us; speedup 1.0000x reference)
//
#include <hip/hip_runtime.h>
#include <cstdint>
#include <cstddef>

#define DM    1024
#define DI    2048
#define DSTATE 16
#define LSEQ  2048
#define BB    2
#define ROWS  (BB * LSEQ)   // 4096
#define NCH   32
#define CLEN  64            // LSEQ / NCH

typedef __bf16 bf16x8 __attribute__((ext_vector_type(8)));
typedef float  f32x4  __attribute__((ext_vector_type(4)));

__device__ __forceinline__ unsigned short f2bf(float f) {
    unsigned u = __float_as_uint(f);
    u += 0x7fffu + ((u >> 16) & 1u);
    return (unsigned short)(u >> 16);
}
__device__ __forceinline__ float bf2f(unsigned short h) {
    return __uint_as_float(((unsigned)h) << 16);
}

// ---------------- weight fp32 -> bf16 conversion (4 arrays, one launch) ----
__global__ void cvt_weights(const float* __restrict__ w0, const float* __restrict__ w1,
                            const float* __restrict__ w2, const float* __restrict__ w3,
                            unsigned short* __restrict__ o0, unsigned short* __restrict__ o1,
                            unsigned short* __restrict__ o2, unsigned short* __restrict__ o3,
                            int n0, int n1, int n2, int n3) {
    int total = n0 + n1 + n2 + n3;
    for (int i = blockIdx.x * blockDim.x + threadIdx.x; i < total; i += gridDim.x * blockDim.x) {
        int j = i;
        if (j < n0) { o0[j] = f2bf(w0[j]); continue; }
        j -= n0;
        if (j < n1) { o1[j] = f2bf(w1[j]); continue; }
        j -= n1;
        if (j < n2) { o2[j] = f2bf(w2[j]); continue; }
        j -= n2;
        o3[j] = f2bf(w3[j]);
    }
}

// ---------------- LayerNorm: one block per row, out bf16 -------------------
__global__ __launch_bounds__(256) void ln_kernel(const float* __restrict__ hs,
                                                 const float* __restrict__ g,
                                                 const float* __restrict__ bta,
                                                 unsigned short* __restrict__ out) {
    const int row = blockIdx.x;
    const int t = threadIdx.x;
    float4 v = ((const float4*)(hs + (size_t)row * DM))[t];
    float s  = v.x + v.y + v.z + v.w;
    float s2 = v.x * v.x + v.y * v.y + v.z * v.z + v.w * v.w;
    #pragma unroll
    for (int o = 32; o > 0; o >>= 1) {
        s  += __shfl_down(s, o);
        s2 += __shfl_down(s2, o);
    }
    __shared__ float r1[4], r2[4];
    if ((t & 63) == 0) { r1[t >> 6] = s; r2[t >> 6] = s2; }
    __syncthreads();
    s  = r1[0] + r1[1] + r1[2] + r1[3];
    s2 = r2[0] + r2[1] + r2[2] + r2[3];
    float mu  = s * (1.f / DM);
    float var = s2 * (1.f / DM) - mu * mu;
    float rs  = rsqrtf(var + 1e-5f);
    float4 gv = ((const float4*)g)[t];
    float4 bv = ((const float4*)bta)[t];
    ushort4 o;
    o.x = f2bf((v.x - mu) * rs * gv.x + bv.x);
    o.y = f2bf((v.y - mu) * rs * gv.y + bv.y);
    o.z = f2bf((v.z - mu) * rs * gv.z + bv.z);
    o.w = f2bf((v.w - mu) * rs * gv.w + bv.w);
    ((ushort4*)out)[(size_t)row * (DM / 4) + t] = o;
}

// ---------------- bf16 MFMA GEMM: out[M][N] = A[M][K] * W[N][K]^T ----------
// EPI 0: write bf16 out
// EPI 1: write fp32 out; also write bf16 of cols<64 to dtOut (x_proj)
// EPI 2: write fp32 out + resid (out_proj)
template <int WAVES_M, int WAVES_N, int WM_T, int WN_T, int EPI>
__global__ __launch_bounds__(WAVES_M * WAVES_N * 64) void gemm_bf16(
    const unsigned short* __restrict__ A, const unsigned short* __restrict__ Bw,
    float* __restrict__ outF, unsigned short* __restrict__ outB,
    const float* __restrict__ resid, unsigned short* __restrict__ dtOut,
    int M, int N, int K) {
    constexpr int BM  = WAVES_M * WM_T * 16;
    constexpr int BN  = WAVES_N * WN_T * 16;
    constexpr int BK  = 32;
    constexpr int LDA = BK + 8;  // pad to break bank-power-of-2 strides
    constexpr int NT  = WAVES_M * WAVES_N * 64;
    __shared__ __align__(16) unsigned short As[BM * LDA];
    __shared__ __align__(16) unsigned short Bs[BN * LDA];

    const int tid  = threadIdx.x;
    const int lane = tid & 63;
    const int wave = tid >> 6;
    const int wm = wave / WAVES_N;
    const int wn = wave % WAVES_N;
    const int rowBase = blockIdx.x * BM;
    const int colBase = blockIdx.y * BN;

    f32x4 acc[WM_T][WN_T];
    #pragma unroll
    for (int i = 0; i < WM_T; ++i)
        #pragma unroll
        for (int j = 0; j < WN_T; ++j) acc[i][j] = (f32x4){0.f, 0.f, 0.f, 0.f};

    for (int k0 = 0; k0 < K; k0 += BK) {
        #pragma unroll 2
        for (int i = tid; i < BM * (BK / 8); i += NT) {
            int r = i >> 2, c = (i & 3) * 8;
            *(uint4*)(As + r * LDA + c) =
                *(const uint4*)(A + (size_t)(rowBase + r) * K + k0 + c);
        }
        #pragma unroll 2
        for (int i = tid; i < BN * (BK / 8); i += NT) {
            int r = i >> 2, c = (i & 3) * 8;
            *(uint4*)(Bs + r * LDA + c) =
                *(const uint4*)(Bw + (size_t)(colBase + r) * K + k0 + c);
        }
        __syncthreads();
        const int koff = (lane >> 4) * 8;
        const int rr = lane & 15;
        bf16x8 a[WM_T], b[WN_T];
        #pragma unroll
        for (int i = 0; i < WM_T; ++i)
            a[i] = *(const bf16x8*)(As + (wm * WM_T * 16 + i * 16 + rr) * LDA + koff);
        #pragma unroll
        for (int j = 0; j < WN_T; ++j)
            b[j] = *(const bf16x8*)(Bs + (wn * WN_T * 16 + j * 16 + rr) * LDA + koff);
        #pragma unroll
        for (int i = 0; i < WM_T; ++i)
            #pragma unroll
            for (int j = 0; j < WN_T; ++j)
                acc[i][j] = __builtin_amdgcn_mfma_f32_16x16x32_bf16(a[i], b[j], acc[i][j], 0, 0, 0);
        __syncthreads();
    }

    const int col0 = colBase + wn * WN_T * 16 + (lane & 15);
    const int row0 = rowBase + wm * WM_T * 16 + (lane >> 4) * 4;
    #pragma unroll
    for (int i = 0; i < WM_T; ++i) {
        #pragma unroll
        for (int j = 0; j < WN_T; ++j) {
            #pragma unroll
            for (int r = 0; r < 4; ++r) {
                int row = row0 + i * 16 + r;
                int col = col0 + j * 16;
                float v = acc[i][j][r];
                size_t idx = (size_t)row * N + col;
                if (EPI == 0) {
                    outB[idx] = f2bf(v);
                } else if (EPI == 1) {
                    outF[idx] = v;
                    if (col < 64) dtOut[(size_t)row * 64 + col] = f2bf(v);
                } else {
                    outF[idx] = v + resid[idx];
                }
            }
        }
    }
}

// ---------------- depthwise causal conv (k=4) + silu -----------------------
__global__ __launch_bounds__(256) void conv_silu(const unsigned short* __restrict__ xz,
                                                 const float* __restrict__ cw,
                                                 const float* __restrict__ cb,
                                                 unsigned short* __restrict__ xc) {
    int tid = blockIdx.x * blockDim.x + threadIdx.x;  // ROWS*DI
    int d  = tid & (DI - 1);
    int bl = tid >> 11;
    int l  = bl & (LSEQ - 1);
    float4 w = ((const float4*)cw)[d];
    float wj[4] = {w.x, w.y, w.z, w.w};
    float accv = cb[d];
    #pragma unroll
    for (int j = 0; j < 4; ++j) {
        int ll = l - 3 + j;
        if (ll >= 0)
            accv += bf2f(xz[(size_t)(bl - 3 + j) * (2 * DI) + d]) * wj[j];
    }
    float s = accv / (1.f + __expf(-accv));
    xc[tid] = f2bf(s);
}

// ---------------- selective scan: chunked parallel scan --------------------
// lane -> channel d (64 consecutive d per wave); wave -> (b, chunk, dgroup)
__device__ __forceinline__ void scan_ids(int& b, int& chunk, int& d) {
    int wid  = (blockIdx.x * blockDim.x + threadIdx.x) >> 6;
    int lane = threadIdx.x & 63;
    int dg   = wid & 31;
    chunk    = (wid >> 5) & 31;
    b        = wid >> 10;
    d        = dg * 64 + lane;
}

__device__ __forceinline__ void load_A(const float* __restrict__ A_log, int d, float* Aa) {
    const float4* Ap = (const float4*)(A_log + (size_t)d * DSTATE);
    float4 a0 = Ap[0], a1 = Ap[1], a2 = Ap[2], a3 = Ap[3];
    float t[16] = {a0.x, a0.y, a0.z, a0.w, a1.x, a1.y, a1.z, a1.w,
                   a2.x, a2.y, a2.z, a2.w, a3.x, a3.y, a3.z, a3.w};
    #pragma unroll
    for (int s = 0; s < DSTATE; ++s) Aa[s] = -__expf(t[s]);
}

__global__ __launch_bounds__(256) void scan_pass1(
    const unsigned short* __restrict__ dtl, const float* __restrict__ dtb,
    const unsigned short* __restrict__ xc, const float* __restrict__ xdbl,
    const float* __restrict__ A_log,
    float* __restrict__ chP, float* __restrict__ chH) {
    int b, chunk, d;
    scan_ids(b, chunk, d);
    float Aa[DSTATE];
    load_A(A_log, d, Aa);
    float bias = dtb[d];
    float P[DSTATE], h[DSTATE];
    #pragma unroll
    for (int s = 0; s < DSTATE; ++s) { P[s] = 1.f; h[s] = 0.f; }
    int l0 = chunk * CLEN;
    for (int il = 0; il < CLEN; ++il) {
        size_t row = (size_t)b * LSEQ + l0 + il;
        float q  = bf2f(dtl[row * DI + d]) + bias;
        float dt = (q > 15.f) ? q : log1pf(__expf(q));
        float xv = bf2f(xc[row * DI + d]);
        const float4* Bp = (const float4*)(xdbl + row * 96 + 64);
        float4 b0 = Bp[0], b1 = Bp[1], b2 = Bp[2], b3 = Bp[3];
        float Bv[16] = {b0.x, b0.y, b0.z, b0.w, b1.x, b1.y, b1.z, b1.w,
                        b2.x, b2.y, b2.z, b2.w, b3.x, b3.y, b3.z, b3.w};
        float dtx = dt * xv;
        #pragma unroll
        for (int s = 0; s < DSTATE; ++s) {
            float dA = __expf(dt * Aa[s]);
            h[s] = dA * h[s] + dtx * Bv[s];
            P[s] *= dA;
        }
    }
    size_t base = ((size_t)(b * NCH + chunk) * DSTATE) * DI + d;
    #pragma unroll
    for (int s = 0; s < DSTATE; ++s) {
        chP[base + (size_t)s * DI] = P[s];
        chH[base + (size_t)s * DI] = h[s];
    }
}

__global__ __launch_bounds__(256) void scan_combine(const float* __restrict__ chP,
                                                    const float* __restrict__ chH,
                                                    float* __restrict__ hInit) {
    int tid = blockIdx.x * blockDim.x + threadIdx.x;  // BB*DSTATE*DI
    int d = tid & (DI - 1);
    int s = (tid >> 11) & 15;
    int b = tid >> 15;
    float H = 0.f;
    for (int c = 0; c < NCH; ++c) {
        size_t base = ((size_t)((b * NCH + c) * DSTATE) + s) * DI + d;
        hInit[base] = H;
        H = chP[base] * H + chH[base];
    }
}

__global__ __launch_bounds__(256) void scan_pass2(
    const unsigned short* __restrict__ dtl, const float* __restrict__ dtb,
    const unsigned short* __restrict__ xc, const float* __restrict__ xdbl,
    const float* __restrict__ A_log, const float* __restrict__ hInit,
    const float* __restrict__ Dp, const unsigned short* __restrict__ xz,
    unsigned short* __restrict__ y) {
    int b, chunk, d;
    scan_ids(b, chunk, d);
    float Aa[DSTATE];
    load_A(A_log, d, Aa);
    float bias = dtb[d];
    float Dd = Dp[d];
    float h[DSTATE];
    size_t base = ((size_t)(b * NCH + chunk) * DSTATE) * DI + d;
    #pragma unroll
    for (int s = 0; s < DSTATE; ++s) h[s] = hInit[base + (size_t)s * DI];
    int l0 = chunk * CLEN;
    for (int il = 0; il < CLEN; ++il) {
        size_t row = (size_t)b * LSEQ + l0 + il;
        float q  = bf2f(dtl[row * DI + d]) + bias;
        float dt = (q > 15.f) ? q : log1pf(__expf(q));
        float xv = bf2f(xc[row * DI + d]);
        const float4* Bp = (const float4*)(xdbl + row * 96 + 64);
        float4 b0 = Bp[0], b1 = Bp[1], b2 = Bp[2], b3 = Bp[3];
        const float4* Cp = (const float4*)(xdbl + row * 96 + 80);
        float4 c0 = Cp[0], c1 = Cp[1], c2 = Cp[2], c3 = Cp[3];
        float Bv[16] = {b0.x, b0.y, b0.z, b0.w, b1.x, b1.y, b1.z, b1.w,
                        b2.x, b2.y, b2.z, b2.w, b3.x, b3.y, b3.z, b3.w};
        float Cv[16] = {c0.x, c0.y, c0.z, c0.w, c1.x, c1.y, c1.z, c1.w,
                        c2.x, c2.y, c2.z, c2.w, c3.x, c3.y, c3.z, c3.w};
        float dtx = dt * xv;
        float yv = 0.f;
        #pragma unroll
        for (int s = 0; s < DSTATE; ++s) {
            float dA = __expf(dt * Aa[s]);
            h[s] = dA * h[s] + dtx * Bv[s];
            yv += h[s] * Cv[s];
        }
        float z = bf2f(xz[row * (2 * DI) + DI + d]);
        float gt = z / (1.f + __expf(-z));
        y[row * DI + d] = f2bf((yv + xv * Dd) * gt);
    }
}

// ---------------- launch ---------------------------------------------------
extern "C" void kernel_launch(void* const* d_in, const int* in_sizes, int n_in,
                              void* d_out, int out_size, void* d_ws, size_t ws_size,
                              hipStream_t stream) {
    (void)in_sizes; (void)n_in; (void)out_size; (void)ws_size;
    const float* hs    = (const float*)d_in[0];
    const float* ln_g  = (const float*)d_in[1];
    const float* ln_b  = (const float*)d_in[2];
    const float* w_in  = (const float*)d_in[3];
    const float* cw    = (const float*)d_in[4];
    const float* cb    = (const float*)d_in[5];
    const float* w_x   = (const float*)d_in[6];
    const float* w_dt  = (const float*)d_in[7];
    const float* dtb   = (const float*)d_in[8];
    const float* A_log = (const float*)d_in[9];
    const float* Dp    = (const float*)d_in[10];
    const float* w_out = (const float*)d_in[11];
    float* out = (float*)d_out;

    char* ws = (char*)d_ws;
    size_t off = 0;
    auto alloc = [&](size_t bytes) -> void* {
        void* p = ws + off;
        off += (bytes + 255) & ~(size_t)255;
        return p;
    };
    unsigned short* h_bf    = (unsigned short*)alloc((size_t)ROWS * DM * 2);
    unsigned short* w_in_b  = (unsigned short*)alloc((size_t)2 * DI * DM * 2);
    unsigned short* w_x_b   = (unsigned short*)alloc((size_t)96 * DI * 2);
    unsigned short* w_dt_b  = (unsigned short*)alloc((size_t)DI * 64 * 2);
    unsigned short* w_out_b = (unsigned short*)alloc((size_t)DM * DI * 2);
    unsigned short* xz      = (unsigned short*)alloc((size_t)ROWS * 2 * DI * 2);
    unsigned short* xc      = (unsigned short*)alloc((size_t)ROWS * DI * 2);
    float*          xdbl    = (float*)alloc((size_t)ROWS * 96 * 4);
    unsigned short* dt_in   = (unsigned short*)alloc((size_t)ROWS * 64 * 2);
    unsigned short* dt_lin  = (unsigned short*)alloc((size_t)ROWS * DI * 2);
    float*          chP     = (float*)alloc((size_t)BB * NCH * DSTATE * DI * 4);
    float*          chH     = (float*)alloc((size_t)BB * NCH * DSTATE * DI * 4);
    float*          hI      = (float*)alloc((size_t)BB * NCH * DSTATE * DI * 4);
    unsigned short* yb      = (unsigned short*)alloc((size_t)ROWS * DI * 2);

    cvt_weights<<<2048, 256, 0, stream>>>(w_in, w_x, w_dt, w_out,
                                          w_in_b, w_x_b, w_dt_b, w_out_b,
                                          2 * DI * DM, 96 * DI, DI * 64, DM * DI);
    ln_kernel<<<ROWS, 256, 0, stream>>>(hs, ln_g, ln_b, h_bf);
    // in_proj: [4096,1024] x [4096,1024]^T -> xz bf16 [4096,4096]
    gemm_bf16<2, 2, 4, 4, 0><<<dim3(ROWS / 128, (2 * DI) / 128), 256, 0, stream>>>(
        h_bf, w_in_b, nullptr, xz, nullptr, nullptr, ROWS, 2 * DI, DM);
    conv_silu<<<(ROWS * DI) / 256, 256, 0, stream>>>(xz, cw, cb, xc);
    // x_proj: [4096,2048] x [96,2048]^T -> xdbl fp32 [4096,96] (+ dt_in bf16)
    gemm_bf16<2, 2, 4, 3, 1><<<dim3(ROWS / 128, 1), 256, 0, stream>>>(
        xc, w_x_b, xdbl, nullptr, nullptr, dt_in, ROWS, 96, DI);
    // dt_proj: [4096,64] x [2048,64]^T -> dt_lin bf16 [4096,2048]
    gemm_bf16<2, 2, 4, 4, 0><<<dim3(ROWS / 128, DI / 128), 256, 0, stream>>>(
        dt_in, w_dt_b, nullptr, dt_lin, nullptr, nullptr, ROWS, DI, 64);
    scan_pass1<<<(BB * NCH * 32 * 64) / 256, 256, 0, stream>>>(
        dt_lin, dtb, xc, xdbl, A_log, chP, chH);
    scan_combine<<<(BB * DSTATE * DI) / 256, 256, 0, stream>>>(chP, chH, hI);
    scan_pass2<<<(BB * NCH * 32 * 64) / 256, 256, 0, stream>>>(
        dt_lin, dtb, xc, xdbl, A_log, hI, Dp, xz, yb);
    // out_proj: [4096,2048] x [1024,2048]^T + residual -> out fp32 [4096,1024]
    gemm_bf16<2, 2, 4, 4, 2><<<dim3(ROWS / 128, DM / 128), 256, 0, stream>>>(
        yb, w_out_b, out, nullptr, hs, nullptr, ROWS, DM, DI);
}

// Round 2
// 487.699 us; speedup vs baseline: 1.0873x; 1.0873x over previous
//
#include <hip/hip_runtime.h>
#include <cstdint>
#include <cstddef>

#define DM    1024
#define DI    2048
#define DSTATE 16
#define LSEQ  2048
#define BB    2
#define ROWS  (BB * LSEQ)   // 4096
#define NCH   64
#define CLEN  32            // LSEQ / NCH

typedef __bf16 bf16x8 __attribute__((ext_vector_type(8)));
typedef float  f32x4  __attribute__((ext_vector_type(4)));

__device__ __forceinline__ unsigned short f2bf(float f) {
    unsigned u = __float_as_uint(f);
    u += 0x7fffu + ((u >> 16) & 1u);
    return (unsigned short)(u >> 16);
}
__device__ __forceinline__ float bf2f(unsigned short h) {
    return __uint_as_float(((unsigned)h) << 16);
}

// ---------------- weight fp32 -> bf16 conversion (4 arrays, one launch) ----
__global__ void cvt_weights(const float* __restrict__ w0, const float* __restrict__ w1,
                            const float* __restrict__ w2, const float* __restrict__ w3,
                            unsigned short* __restrict__ o0, unsigned short* __restrict__ o1,
                            unsigned short* __restrict__ o2, unsigned short* __restrict__ o3,
                            int n0, int n1, int n2, int n3) {
    int total = n0 + n1 + n2 + n3;
    for (int i = blockIdx.x * blockDim.x + threadIdx.x; i < total; i += gridDim.x * blockDim.x) {
        int j = i;
        if (j < n0) { o0[j] = f2bf(w0[j]); continue; }
        j -= n0;
        if (j < n1) { o1[j] = f2bf(w1[j]); continue; }
        j -= n1;
        if (j < n2) { o2[j] = f2bf(w2[j]); continue; }
        j -= n2;
        o3[j] = f2bf(w3[j]);
    }
}

// ---------------- LayerNorm: one block per row, out bf16 -------------------
__global__ __launch_bounds__(256) void ln_kernel(const float* __restrict__ hs,
                                                 const float* __restrict__ g,
                                                 const float* __restrict__ bta,
                                                 unsigned short* __restrict__ out) {
    const int row = blockIdx.x;
    const int t = threadIdx.x;
    float4 v = ((const float4*)(hs + (size_t)row * DM))[t];
    float s  = v.x + v.y + v.z + v.w;
    float s2 = v.x * v.x + v.y * v.y + v.z * v.z + v.w * v.w;
    #pragma unroll
    for (int o = 32; o > 0; o >>= 1) {
        s  += __shfl_down(s, o);
        s2 += __shfl_down(s2, o);
    }
    __shared__ float r1[4], r2[4];
    if ((t & 63) == 0) { r1[t >> 6] = s; r2[t >> 6] = s2; }
    __syncthreads();
    s  = r1[0] + r1[1] + r1[2] + r1[3];
    s2 = r2[0] + r2[1] + r2[2] + r2[3];
    float mu  = s * (1.f / DM);
    float var = s2 * (1.f / DM) - mu * mu;
    float rs  = rsqrtf(var + 1e-5f);
    float4 gv = ((const float4*)g)[t];
    float4 bv = ((const float4*)bta)[t];
    ushort4 o;
    o.x = f2bf((v.x - mu) * rs * gv.x + bv.x);
    o.y = f2bf((v.y - mu) * rs * gv.y + bv.y);
    o.z = f2bf((v.z - mu) * rs * gv.z + bv.z);
    o.w = f2bf((v.w - mu) * rs * gv.w + bv.w);
    ((ushort4*)out)[(size_t)row * (DM / 4) + t] = o;
}

// ---------------- bf16 MFMA GEMM: out[M][N] = A[M][K] * W[N][K]^T ----------
// EPI 0: write bf16 out
// EPI 1: write fp32 out; also write bf16 of cols<64 to dtOut (x_proj)
// EPI 2: write fp32 out + resid (out_proj)
template <int WAVES_M, int WAVES_N, int WM_T, int WN_T, int EPI>
__global__ __launch_bounds__(WAVES_M * WAVES_N * 64) void gemm_bf16(
    const unsigned short* __restrict__ A, const unsigned short* __restrict__ Bw,
    float* __restrict__ outF, unsigned short* __restrict__ outB,
    const float* __restrict__ resid, unsigned short* __restrict__ dtOut,
    int M, int N, int K) {
    constexpr int BM  = WAVES_M * WM_T * 16;
    constexpr int BN  = WAVES_N * WN_T * 16;
    constexpr int BK  = 32;
    constexpr int LDA = BK + 8;  // pad to break bank-power-of-2 strides
    constexpr int NT  = WAVES_M * WAVES_N * 64;
    __shared__ __align__(16) unsigned short As[BM * LDA];
    __shared__ __align__(16) unsigned short Bs[BN * LDA];

    const int tid  = threadIdx.x;
    const int lane = tid & 63;
    const int wave = tid >> 6;
    const int wm = wave / WAVES_N;
    const int wn = wave % WAVES_N;
    const int rowBase = blockIdx.x * BM;
    const int colBase = blockIdx.y * BN;

    f32x4 acc[WM_T][WN_T];
    #pragma unroll
    for (int i = 0; i < WM_T; ++i)
        #pragma unroll
        for (int j = 0; j < WN_T; ++j) acc[i][j] = (f32x4){0.f, 0.f, 0.f, 0.f};

    for (int k0 = 0; k0 < K; k0 += BK) {
        #pragma unroll 2
        for (int i = tid; i < BM * (BK / 8); i += NT) {
            int r = i >> 2, c = (i & 3) * 8;
            *(uint4*)(As + r * LDA + c) =
                *(const uint4*)(A + (size_t)(rowBase + r) * K + k0 + c);
        }
        #pragma unroll 2
        for (int i = tid; i < BN * (BK / 8); i += NT) {
            int r = i >> 2, c = (i & 3) * 8;
            *(uint4*)(Bs + r * LDA + c) =
                *(const uint4*)(Bw + (size_t)(colBase + r) * K + k0 + c);
        }
        __syncthreads();
        const int koff = (lane >> 4) * 8;
        const int rr = lane & 15;
        bf16x8 a[WM_T], b[WN_T];
        #pragma unroll
        for (int i = 0; i < WM_T; ++i)
            a[i] = *(const bf16x8*)(As + (wm * WM_T * 16 + i * 16 + rr) * LDA + koff);
        #pragma unroll
        for (int j = 0; j < WN_T; ++j)
            b[j] = *(const bf16x8*)(Bs + (wn * WN_T * 16 + j * 16 + rr) * LDA + koff);
        #pragma unroll
        for (int i = 0; i < WM_T; ++i)
            #pragma unroll
            for (int j = 0; j < WN_T; ++j)
                acc[i][j] = __builtin_amdgcn_mfma_f32_16x16x32_bf16(a[i], b[j], acc[i][j], 0, 0, 0);
        __syncthreads();
    }

    const int col0 = colBase + wn * WN_T * 16 + (lane & 15);
    const int row0 = rowBase + wm * WM_T * 16 + (lane >> 4) * 4;
    #pragma unroll
    for (int i = 0; i < WM_T; ++i) {
        #pragma unroll
        for (int j = 0; j < WN_T; ++j) {
            #pragma unroll
            for (int r = 0; r < 4; ++r) {
                int row = row0 + i * 16 + r;
                int col = col0 + j * 16;
                float v = acc[i][j][r];
                size_t idx = (size_t)row * N + col;
                if (EPI == 0) {
                    outB[idx] = f2bf(v);
                } else if (EPI == 1) {
                    outF[idx] = v;
                    if (col < 64) dtOut[(size_t)row * 64 + col] = f2bf(v);
                } else {
                    outF[idx] = v + resid[idx];
                }
            }
        }
    }
}

// ---------------- depthwise causal conv (k=4) + silu -----------------------
__global__ __launch_bounds__(256) void conv_silu(const unsigned short* __restrict__ xz,
                                                 const float* __restrict__ cw,
                                                 const float* __restrict__ cb,
                                                 unsigned short* __restrict__ xc) {
    int tid = blockIdx.x * blockDim.x + threadIdx.x;  // ROWS*DI
    int d  = tid & (DI - 1);
    int bl = tid >> 11;
    int l  = bl & (LSEQ - 1);
    float4 w = ((const float4*)cw)[d];
    float wj[4] = {w.x, w.y, w.z, w.w};
    float accv = cb[d];
    #pragma unroll
    for (int j = 0; j < 4; ++j) {
        int ll = l - 3 + j;
        if (ll >= 0)
            accv += bf2f(xz[(size_t)(bl - 3 + j) * (2 * DI) + d]) * wj[j];
    }
    float s = accv / (1.f + __expf(-accv));
    xc[tid] = f2bf(s);
}

// ---------------- selective scan: chunked parallel scan --------------------
// lane -> channel d (64 consecutive d per wave); wave -> (b, chunk, dgroup)
__device__ __forceinline__ void scan_ids(int& b, int& chunk, int& d) {
    int wid  = (blockIdx.x * blockDim.x + threadIdx.x) >> 6;
    int lane = threadIdx.x & 63;
    int dg   = wid & 31;
    chunk    = (wid >> 5) & (NCH - 1);
    b        = wid >> 11;
    d        = dg * 64 + lane;
}

// Ab[s] = -exp(A_log[d][s]) * log2(e)  -> dA = exp2(dt * Ab[s])
__device__ __forceinline__ void load_A(const float* __restrict__ A_log, int d, float* Ab) {
    const float4* Ap = (const float4*)(A_log + (size_t)d * DSTATE);
    float4 a0 = Ap[0], a1 = Ap[1], a2 = Ap[2], a3 = Ap[3];
    float t[16] = {a0.x, a0.y, a0.z, a0.w, a1.x, a1.y, a1.z, a1.w,
                   a2.x, a2.y, a2.z, a2.w, a3.x, a3.y, a3.z, a3.w};
    #pragma unroll
    for (int s = 0; s < DSTATE; ++s) Ab[s] = -__expf(t[s]) * 1.44269504f;
}

__device__ __forceinline__ float softplus_fast(float q) {
    return (q > 15.f) ? q : __logf(1.f + __expf(q));
}

__global__ __launch_bounds__(256) void scan_pass1(
    const unsigned short* __restrict__ dtl, const float* __restrict__ dtb,
    const unsigned short* __restrict__ xc, const float* __restrict__ xdbl,
    const float* __restrict__ A_log,
    float* __restrict__ chP, float* __restrict__ chH) {
    int b, chunk, d;
    scan_ids(b, chunk, d);
    float Ab[DSTATE];
    load_A(A_log, d, Ab);
    float bias = dtb[d];
    float P[DSTATE], h[DSTATE];
    #pragma unroll
    for (int s = 0; s < DSTATE; ++s) { P[s] = 1.f; h[s] = 0.f; }
    int l0 = chunk * CLEN;
    for (int il = 0; il < CLEN; ++il) {
        size_t row = (size_t)b * LSEQ + l0 + il;
        float q  = bf2f(dtl[row * DI + d]) + bias;
        float dt = softplus_fast(q);
        float xv = bf2f(xc[row * DI + d]);
        const float4* Bp = (const float4*)(xdbl + row * 96 + 64);
        float4 b0 = Bp[0], b1 = Bp[1], b2 = Bp[2], b3 = Bp[3];
        float Bv[16] = {b0.x, b0.y, b0.z, b0.w, b1.x, b1.y, b1.z, b1.w,
                        b2.x, b2.y, b2.z, b2.w, b3.x, b3.y, b3.z, b3.w};
        float dtx = dt * xv;
        #pragma unroll
        for (int s = 0; s < DSTATE; ++s) {
            float dA = exp2f(dt * Ab[s]);
            h[s] = dA * h[s] + dtx * Bv[s];
            P[s] *= dA;
        }
    }
    size_t base = ((size_t)(b * NCH + chunk) * DSTATE) * DI + d;
    #pragma unroll
    for (int s = 0; s < DSTATE; ++s) {
        chP[base + (size_t)s * DI] = P[s];
        chH[base + (size_t)s * DI] = h[s];
    }
}

__global__ __launch_bounds__(256) void scan_combine(const float* __restrict__ chP,
                                                    const float* __restrict__ chH,
                                                    float* __restrict__ hInit) {
    int tid = blockIdx.x * blockDim.x + threadIdx.x;  // BB*DSTATE*DI
    int d = tid & (DI - 1);
    int s = (tid >> 11) & 15;
    int b = tid >> 15;
    float H = 0.f;
    for (int c = 0; c < NCH; ++c) {
        size_t base = ((size_t)((b * NCH + c) * DSTATE) + s) * DI + d;
        hInit[base] = H;
        H = chP[base] * H + chH[base];
    }
}

__global__ __launch_bounds__(256) void scan_pass2(
    const unsigned short* __restrict__ dtl, const float* __restrict__ dtb,
    const unsigned short* __restrict__ xc, const float* __restrict__ xdbl,
    const float* __restrict__ A_log, const float* __restrict__ hInit,
    const float* __restrict__ Dp, const unsigned short* __restrict__ xz,
    unsigned short* __restrict__ y) {
    int b, chunk, d;
    scan_ids(b, chunk, d);
    float Ab[DSTATE];
    load_A(A_log, d, Ab);
    float bias = dtb[d];
    float Dd = Dp[d];
    float h[DSTATE];
    size_t base = ((size_t)(b * NCH + chunk) * DSTATE) * DI + d;
    #pragma unroll
    for (int s = 0; s < DSTATE; ++s) h[s] = hInit[base + (size_t)s * DI];
    int l0 = chunk * CLEN;
    for (int il = 0; il < CLEN; ++il) {
        size_t row = (size_t)b * LSEQ + l0 + il;
        float q  = bf2f(dtl[row * DI + d]) + bias;
        float dt = softplus_fast(q);
        float xv = bf2f(xc[row * DI + d]);
        const float4* Bp = (const float4*)(xdbl + row * 96 + 64);
        float4 b0 = Bp[0], b1 = Bp[1], b2 = Bp[2], b3 = Bp[3];
        const float4* Cp = (const float4*)(xdbl + row * 96 + 80);
        float4 c0 = Cp[0], c1 = Cp[1], c2 = Cp[2], c3 = Cp[3];
        float Bv[16] = {b0.x, b0.y, b0.z, b0.w, b1.x, b1.y, b1.z, b1.w,
                        b2.x, b2.y, b2.z, b2.w, b3.x, b3.y, b3.z, b3.w};
        float Cv[16] = {c0.x, c0.y, c0.z, c0.w, c1.x, c1.y, c1.z, c1.w,
                        c2.x, c2.y, c2.z, c2.w, c3.x, c3.y, c3.z, c3.w};
        float dtx = dt * xv;
        float yv = 0.f;
        #pragma unroll
        for (int s = 0; s < DSTATE; ++s) {
            float dA = exp2f(dt * Ab[s]);
            h[s] = dA * h[s] + dtx * Bv[s];
            yv += h[s] * Cv[s];
        }
        float z = bf2f(xz[row * (2 * DI) + DI + d]);
        float gt = z / (1.f + __expf(-z));
        y[row * DI + d] = f2bf((yv + xv * Dd) * gt);
    }
}

// ---------------- launch ---------------------------------------------------
extern "C" void kernel_launch(void* const* d_in, const int* in_sizes, int n_in,
                              void* d_out, int out_size, void* d_ws, size_t ws_size,
                              hipStream_t stream) {
    (void)in_sizes; (void)n_in; (void)out_size; (void)ws_size;
    const float* hs    = (const float*)d_in[0];
    const float* ln_g  = (const float*)d_in[1];
    const float* ln_b  = (const float*)d_in[2];
    const float* w_in  = (const float*)d_in[3];
    const float* cw    = (const float*)d_in[4];
    const float* cb    = (const float*)d_in[5];
    const float* w_x   = (const float*)d_in[6];
    const float* w_dt  = (const float*)d_in[7];
    const float* dtb   = (const float*)d_in[8];
    const float* A_log = (const float*)d_in[9];
    const float* Dp    = (const float*)d_in[10];
    const float* w_out = (const float*)d_in[11];
    float* out = (float*)d_out;

    char* ws = (char*)d_ws;
    size_t off = 0;
    auto alloc = [&](size_t bytes) -> void* {
        void* p = ws + off;
        off += (bytes + 255) & ~(size_t)255;
        return p;
    };
    unsigned short* h_bf    = (unsigned short*)alloc((size_t)ROWS * DM * 2);
    unsigned short* w_in_b  = (unsigned short*)alloc((size_t)2 * DI * DM * 2);
    unsigned short* w_x_b   = (unsigned short*)alloc((size_t)96 * DI * 2);
    unsigned short* w_dt_b  = (unsigned short*)alloc((size_t)DI * 64 * 2);
    unsigned short* w_out_b = (unsigned short*)alloc((size_t)DM * DI * 2);
    unsigned short* xz      = (unsigned short*)alloc((size_t)ROWS * 2 * DI * 2);
    unsigned short* xc      = (unsigned short*)alloc((size_t)ROWS * DI * 2);
    float*          xdbl    = (float*)alloc((size_t)ROWS * 96 * 4);
    unsigned short* dt_in   = (unsigned short*)alloc((size_t)ROWS * 64 * 2);
    unsigned short* dt_lin  = (unsigned short*)alloc((size_t)ROWS * DI * 2);
    float*          chP     = (float*)alloc((size_t)BB * NCH * DSTATE * DI * 4);
    float*          chH     = (float*)alloc((size_t)BB * NCH * DSTATE * DI * 4);
    float*          hI      = (float*)alloc((size_t)BB * NCH * DSTATE * DI * 4);
    unsigned short* yb      = (unsigned short*)alloc((size_t)ROWS * DI * 2);

    cvt_weights<<<2048, 256, 0, stream>>>(w_in, w_x, w_dt, w_out,
                                          w_in_b, w_x_b, w_dt_b, w_out_b,
                                          2 * DI * DM, 96 * DI, DI * 64, DM * DI);
    ln_kernel<<<ROWS, 256, 0, stream>>>(hs, ln_g, ln_b, h_bf);
    // in_proj: [4096,1024] x [4096,1024]^T -> xz bf16 [4096,4096]
    gemm_bf16<2, 2, 4, 4, 0><<<dim3(ROWS / 128, (2 * DI) / 128), 256, 0, stream>>>(
        h_bf, w_in_b, nullptr, xz, nullptr, nullptr, ROWS, 2 * DI, DM);
    conv_silu<<<(ROWS * DI) / 256, 256, 0, stream>>>(xz, cw, cb, xc);
    // x_proj: [4096,2048] x [96,2048]^T -> xdbl fp32 [4096,96] (+ dt_in bf16)
    gemm_bf16<2, 2, 4, 3, 1><<<dim3(ROWS / 128, 1), 256, 0, stream>>>(
        xc, w_x_b, xdbl, nullptr, nullptr, dt_in, ROWS, 96, DI);
    // dt_proj: [4096,64] x [2048,64]^T -> dt_lin bf16 [4096,2048]
    gemm_bf16<2, 2, 4, 4, 0><<<dim3(ROWS / 128, DI / 128), 256, 0, stream>>>(
        dt_in, w_dt_b, nullptr, dt_lin, nullptr, nullptr, ROWS, DI, 64);
    scan_pass1<<<(BB * NCH * 32 * 64) / 256, 256, 0, stream>>>(
        dt_lin, dtb, xc, xdbl, A_log, chP, chH);
    scan_combine<<<(BB * DSTATE * DI) / 256, 256, 0, stream>>>(chP, chH, hI);
    scan_pass2<<<(BB * NCH * 32 * 64) / 256, 256, 0, stream>>>(
        dt_lin, dtb, xc, xdbl, A_log, hI, Dp, xz, yb);
    // out_proj: [4096,2048] x [1024,2048]^T + residual -> out fp32 [4096,1024]
    gemm_bf16<2, 2, 4, 4, 2><<<dim3(ROWS / 128, DM / 128), 256, 0, stream>>>(
        yb, w_out_b, out, nullptr, hs, nullptr, ROWS, DM, DI);
}

// Round 3
// 411.576 us; speedup vs baseline: 1.2884x; 1.1850x over previous
//
#include <hip/hip_runtime.h>
#include <cstdint>
#include <cstddef>

#define DM    1024
#define DI    2048
#define DSTATE 16
#define LSEQ  2048
#define BB    2
#define ROWS  (BB * LSEQ)   // 4096
#define NCH   64
#define CLEN  32            // LSEQ / NCH

typedef __bf16 bf16x8 __attribute__((ext_vector_type(8)));
typedef float  f32x4  __attribute__((ext_vector_type(4)));

__device__ __forceinline__ unsigned short f2bf(float f) {
    unsigned u = __float_as_uint(f);
    u += 0x7fffu + ((u >> 16) & 1u);
    return (unsigned short)(u >> 16);
}
__device__ __forceinline__ float bf2f(unsigned short h) {
    return __uint_as_float(((unsigned)h) << 16);
}

// async global->LDS, 16B per lane, wave-uniform LDS base (HW scatters lane*16)
__device__ __forceinline__ void gld_lds16(const void* g, void* l) {
    __builtin_amdgcn_global_load_lds(
        (const __attribute__((address_space(1))) unsigned int*)g,
        (__attribute__((address_space(3))) unsigned int*)l,
        16, 0, 0);
}

// ---------------- weight fp32 -> bf16 conversion (vectorized) --------------
__global__ void cvt_weights(const float4* __restrict__ w0, const float4* __restrict__ w1,
                            const float4* __restrict__ w2, const float4* __restrict__ w3,
                            ushort4* __restrict__ o0, ushort4* __restrict__ o1,
                            ushort4* __restrict__ o2, ushort4* __restrict__ o3,
                            int n0, int n1, int n2, int n3) {  // counts in float4 units
    int total = n0 + n1 + n2 + n3;
    for (int i = blockIdx.x * blockDim.x + threadIdx.x; i < total; i += gridDim.x * blockDim.x) {
        int j = i;
        const float4* w;
        ushort4* o;
        if (j < n0) { w = w0; o = o0; }
        else { j -= n0;
            if (j < n1) { w = w1; o = o1; }
            else { j -= n1;
                if (j < n2) { w = w2; o = o2; }
                else { j -= n2; w = w3; o = o3; }
            }
        }
        float4 v = w[j];
        ushort4 r;
        r.x = f2bf(v.x); r.y = f2bf(v.y); r.z = f2bf(v.z); r.w = f2bf(v.w);
        o[j] = r;
    }
}

// ---------------- LayerNorm: one block per row, out bf16 -------------------
__global__ __launch_bounds__(256) void ln_kernel(const float* __restrict__ hs,
                                                 const float* __restrict__ g,
                                                 const float* __restrict__ bta,
                                                 unsigned short* __restrict__ out) {
    const int row = blockIdx.x;
    const int t = threadIdx.x;
    float4 v = ((const float4*)(hs + (size_t)row * DM))[t];
    float s  = v.x + v.y + v.z + v.w;
    float s2 = v.x * v.x + v.y * v.y + v.z * v.z + v.w * v.w;
    #pragma unroll
    for (int o = 32; o > 0; o >>= 1) {
        s  += __shfl_down(s, o);
        s2 += __shfl_down(s2, o);
    }
    __shared__ float r1[4], r2[4];
    if ((t & 63) == 0) { r1[t >> 6] = s; r2[t >> 6] = s2; }
    __syncthreads();
    s  = r1[0] + r1[1] + r1[2] + r1[3];
    s2 = r2[0] + r2[1] + r2[2] + r2[3];
    float mu  = s * (1.f / DM);
    float var = s2 * (1.f / DM) - mu * mu;
    float rs  = rsqrtf(var + 1e-5f);
    float4 gv = ((const float4*)g)[t];
    float4 bv = ((const float4*)bta)[t];
    ushort4 o;
    o.x = f2bf((v.x - mu) * rs * gv.x + bv.x);
    o.y = f2bf((v.y - mu) * rs * gv.y + bv.y);
    o.z = f2bf((v.z - mu) * rs * gv.z + bv.z);
    o.w = f2bf((v.w - mu) * rs * gv.w + bv.w);
    ((ushort4*)out)[(size_t)row * (DM / 4) + t] = o;
}

// ---------------- bf16 MFMA GEMM: out[M][N] = A[M][K] * W[N][K]^T ----------
// m97-style: global_load_lds width=16 staging into UNPADDED row-major LDS
// tiles As[BM][32], Bs[BN][32]. One 1KB chunk = 16 rows, staged by one wave
// instruction (lane i -> row i/4, colchunk i%4).
// EPI 0: write bf16 out
// EPI 1: write fp32 out; also write bf16 of cols<64 to dtOut (x_proj)
// EPI 2: write fp32 out + resid (out_proj)
template <int WAVES_M, int WAVES_N, int WM_T, int WN_T, int EPI>
__global__ __launch_bounds__(WAVES_M * WAVES_N * 64) void gemm_bf16(
    const unsigned short* __restrict__ A, const unsigned short* __restrict__ Bw,
    float* __restrict__ outF, unsigned short* __restrict__ outB,
    const float* __restrict__ resid, unsigned short* __restrict__ dtOut,
    int M, int N, int K) {
    constexpr int BM = WAVES_M * WM_T * 16;
    constexpr int BN = WAVES_N * WN_T * 16;
    constexpr int BK = 32;
    constexpr int NT = WAVES_M * WAVES_N * 64;
    constexpr int NW = NT / 64;
    constexpr int CH_A = BM / 16;          // 1KB chunks in A tile
    constexpr int NCHUNK = (BM + BN) / 16;
    __shared__ __align__(1024) unsigned short smem[(BM + BN) * BK];
    unsigned short* As = smem;
    unsigned short* Bs = smem + BM * BK;

    const int tid  = threadIdx.x;
    const int lane = tid & 63;
    const int wave = tid >> 6;
    const int wm = wave / WAVES_N;
    const int wn = wave % WAVES_N;
    const int rowBase = blockIdx.x * BM;
    const int colBase = blockIdx.y * BN;

    f32x4 acc[WM_T][WN_T];
    #pragma unroll
    for (int i = 0; i < WM_T; ++i)
        #pragma unroll
        for (int j = 0; j < WN_T; ++j) acc[i][j] = (f32x4){0.f, 0.f, 0.f, 0.f};

    const int lrow = lane >> 2;            // 0..15 within chunk
    const int lcol = (lane & 3) * 8;       // 0,8,16,24 shorts

    for (int k0 = 0; k0 < K; k0 += BK) {
        for (int c = wave; c < NCHUNK; c += NW) {
            const unsigned short* g;
            if (c < CH_A)
                g = A + (size_t)(rowBase + c * 16 + lrow) * K + k0 + lcol;
            else
                g = Bw + (size_t)(colBase + (c - CH_A) * 16 + lrow) * K + k0 + lcol;
            gld_lds16(g, smem + c * 512);
        }
        __syncthreads();
        const int koff = (lane >> 4) * 8;
        const int rr = lane & 15;
        bf16x8 a[WM_T], b[WN_T];
        #pragma unroll
        for (int i = 0; i < WM_T; ++i)
            a[i] = *(const bf16x8*)(As + (wm * WM_T * 16 + i * 16 + rr) * BK + koff);
        #pragma unroll
        for (int j = 0; j < WN_T; ++j)
            b[j] = *(const bf16x8*)(Bs + (wn * WN_T * 16 + j * 16 + rr) * BK + koff);
        #pragma unroll
        for (int i = 0; i < WM_T; ++i)
            #pragma unroll
            for (int j = 0; j < WN_T; ++j)
                acc[i][j] = __builtin_amdgcn_mfma_f32_16x16x32_bf16(a[i], b[j], acc[i][j], 0, 0, 0);
        __syncthreads();
    }

    const int col0 = colBase + wn * WN_T * 16 + (lane & 15);
    const int row0 = rowBase + wm * WM_T * 16 + (lane >> 4) * 4;
    #pragma unroll
    for (int i = 0; i < WM_T; ++i) {
        #pragma unroll
        for (int j = 0; j < WN_T; ++j) {
            #pragma unroll
            for (int r = 0; r < 4; ++r) {
                int row = row0 + i * 16 + r;
                int col = col0 + j * 16;
                float v = acc[i][j][r];
                size_t idx = (size_t)row * N + col;
                if (EPI == 0) {
                    outB[idx] = f2bf(v);
                } else if (EPI == 1) {
                    outF[idx] = v;
                    if (col < 64) dtOut[(size_t)row * 64 + col] = f2bf(v);
                } else {
                    outF[idx] = v + resid[idx];
                }
            }
        }
    }
}

// ---------------- depthwise causal conv (k=4) + silu -----------------------
__global__ __launch_bounds__(256) void conv_silu(const unsigned short* __restrict__ xz,
                                                 const float* __restrict__ cw,
                                                 const float* __restrict__ cb,
                                                 unsigned short* __restrict__ xc) {
    int tid = blockIdx.x * blockDim.x + threadIdx.x;  // ROWS*DI
    int d  = tid & (DI - 1);
    int bl = tid >> 11;
    int l  = bl & (LSEQ - 1);
    float4 w = ((const float4*)cw)[d];
    float wj[4] = {w.x, w.y, w.z, w.w};
    float accv = cb[d];
    #pragma unroll
    for (int j = 0; j < 4; ++j) {
        int ll = l - 3 + j;
        if (ll >= 0)
            accv += bf2f(xz[(size_t)(bl - 3 + j) * (2 * DI) + d]) * wj[j];
    }
    float s = accv / (1.f + __expf(-accv));
    xc[tid] = f2bf(s);
}

// ---------------- selective scan: chunked parallel scan --------------------
__device__ __forceinline__ void scan_ids(int& b, int& chunk, int& d) {
    int wid  = (blockIdx.x * blockDim.x + threadIdx.x) >> 6;
    int lane = threadIdx.x & 63;
    int dg   = wid & 31;
    chunk    = (wid >> 5) & (NCH - 1);
    b        = wid >> 11;
    d        = dg * 64 + lane;
}

// Ab[s] = -exp(A_log[d][s]) * log2(e)  -> dA = exp2(dt * Ab[s])
__device__ __forceinline__ void load_A(const float* __restrict__ A_log, int d, float* Ab) {
    const float4* Ap = (const float4*)(A_log + (size_t)d * DSTATE);
    float4 a0 = Ap[0], a1 = Ap[1], a2 = Ap[2], a3 = Ap[3];
    float t[16] = {a0.x, a0.y, a0.z, a0.w, a1.x, a1.y, a1.z, a1.w,
                   a2.x, a2.y, a2.z, a2.w, a3.x, a3.y, a3.z, a3.w};
    #pragma unroll
    for (int s = 0; s < DSTATE; ++s) Ab[s] = -__expf(t[s]) * 1.44269504f;
}

__device__ __forceinline__ float softplus_fast(float q) {
    return (q > 15.f) ? q : __logf(1.f + __expf(q));
}

__global__ __launch_bounds__(256) void scan_pass1(
    const unsigned short* __restrict__ dtl, const float* __restrict__ dtb,
    const unsigned short* __restrict__ xc, const float* __restrict__ xdbl,
    const float* __restrict__ A_log,
    float* __restrict__ chP, float* __restrict__ chH) {
    int b, chunk, d;
    scan_ids(b, chunk, d);
    float Ab[DSTATE];
    load_A(A_log, d, Ab);
    float bias = dtb[d];
    float P[DSTATE], h[DSTATE];
    #pragma unroll
    for (int s = 0; s < DSTATE; ++s) { P[s] = 1.f; h[s] = 0.f; }
    int l0 = chunk * CLEN;
    for (int il = 0; il < CLEN; ++il) {
        size_t row = (size_t)b * LSEQ + l0 + il;
        float q  = bf2f(dtl[row * DI + d]) + bias;
        float dt = softplus_fast(q);
        float xv = bf2f(xc[row * DI + d]);
        const float4* Bp = (const float4*)(xdbl + row * 96 + 64);
        float4 b0 = Bp[0], b1 = Bp[1], b2 = Bp[2], b3 = Bp[3];
        float Bv[16] = {b0.x, b0.y, b0.z, b0.w, b1.x, b1.y, b1.z, b1.w,
                        b2.x, b2.y, b2.z, b2.w, b3.x, b3.y, b3.z, b3.w};
        float dtx = dt * xv;
        #pragma unroll
        for (int s = 0; s < DSTATE; ++s) {
            float dA = exp2f(dt * Ab[s]);
            h[s] = dA * h[s] + dtx * Bv[s];
            P[s] *= dA;
        }
    }
    size_t base = ((size_t)(b * NCH + chunk) * DSTATE) * DI + d;
    #pragma unroll
    for (int s = 0; s < DSTATE; ++s) {
        chP[base + (size_t)s * DI] = P[s];
        chH[base + (size_t)s * DI] = h[s];
    }
}

__global__ __launch_bounds__(256) void scan_combine(const float* __restrict__ chP,
                                                    const float* __restrict__ chH,
                                                    float* __restrict__ hInit) {
    int tid = blockIdx.x * blockDim.x + threadIdx.x;  // BB*DSTATE*DI
    int d = tid & (DI - 1);
    int s = (tid >> 11) & 15;
    int b = tid >> 15;
    float H = 0.f;
    for (int c = 0; c < NCH; ++c) {
        size_t base = ((size_t)((b * NCH + c) * DSTATE) + s) * DI + d;
        hInit[base] = H;
        H = chP[base] * H + chH[base];
    }
}

__global__ __launch_bounds__(256) void scan_pass2(
    const unsigned short* __restrict__ dtl, const float* __restrict__ dtb,
    const unsigned short* __restrict__ xc, const float* __restrict__ xdbl,
    const float* __restrict__ A_log, const float* __restrict__ hInit,
    const float* __restrict__ Dp, const unsigned short* __restrict__ xz,
    unsigned short* __restrict__ y) {
    int b, chunk, d;
    scan_ids(b, chunk, d);
    float Ab[DSTATE];
    load_A(A_log, d, Ab);
    float bias = dtb[d];
    float Dd = Dp[d];
    float h[DSTATE];
    size_t base = ((size_t)(b * NCH + chunk) * DSTATE) * DI + d;
    #pragma unroll
    for (int s = 0; s < DSTATE; ++s) h[s] = hInit[base + (size_t)s * DI];
    int l0 = chunk * CLEN;
    for (int il = 0; il < CLEN; ++il) {
        size_t row = (size_t)b * LSEQ + l0 + il;
        float q  = bf2f(dtl[row * DI + d]) + bias;
        float dt = softplus_fast(q);
        float xv = bf2f(xc[row * DI + d]);
        const float4* Bp = (const float4*)(xdbl + row * 96 + 64);
        float4 b0 = Bp[0], b1 = Bp[1], b2 = Bp[2], b3 = Bp[3];
        const float4* Cp = (const float4*)(xdbl + row * 96 + 80);
        float4 c0 = Cp[0], c1 = Cp[1], c2 = Cp[2], c3 = Cp[3];
        float Bv[16] = {b0.x, b0.y, b0.z, b0.w, b1.x, b1.y, b1.z, b1.w,
                        b2.x, b2.y, b2.z, b2.w, b3.x, b3.y, b3.z, b3.w};
        float Cv[16] = {c0.x, c0.y, c0.z, c0.w, c1.x, c1.y, c1.z, c1.w,
                        c2.x, c2.y, c2.z, c2.w, c3.x, c3.y, c3.z, c3.w};
        float dtx = dt * xv;
        float yv = 0.f;
        #pragma unroll
        for (int s = 0; s < DSTATE; ++s) {
            float dA = exp2f(dt * Ab[s]);
            h[s] = dA * h[s] + dtx * Bv[s];
            yv += h[s] * Cv[s];
        }
        float z = bf2f(xz[row * (2 * DI) + DI + d]);
        float gt = z / (1.f + __expf(-z));
        y[row * DI + d] = f2bf((yv + xv * Dd) * gt);
    }
}

// ---------------- launch ---------------------------------------------------
extern "C" void kernel_launch(void* const* d_in, const int* in_sizes, int n_in,
                              void* d_out, int out_size, void* d_ws, size_t ws_size,
                              hipStream_t stream) {
    (void)in_sizes; (void)n_in; (void)out_size; (void)ws_size;
    const float* hs    = (const float*)d_in[0];
    const float* ln_g  = (const float*)d_in[1];
    const float* ln_b  = (const float*)d_in[2];
    const float* w_in  = (const float*)d_in[3];
    const float* cw    = (const float*)d_in[4];
    const float* cb    = (const float*)d_in[5];
    const float* w_x   = (const float*)d_in[6];
    const float* w_dt  = (const float*)d_in[7];
    const float* dtb   = (const float*)d_in[8];
    const float* A_log = (const float*)d_in[9];
    const float* Dp    = (const float*)d_in[10];
    const float* w_out = (const float*)d_in[11];
    float* out = (float*)d_out;

    char* ws = (char*)d_ws;
    size_t off = 0;
    auto alloc = [&](size_t bytes) -> void* {
        void* p = ws + off;
        off += (bytes + 255) & ~(size_t)255;
        return p;
    };
    unsigned short* h_bf    = (unsigned short*)alloc((size_t)ROWS * DM * 2);
    unsigned short* w_in_b  = (unsigned short*)alloc((size_t)2 * DI * DM * 2);
    unsigned short* w_x_b   = (unsigned short*)alloc((size_t)96 * DI * 2);
    unsigned short* w_dt_b  = (unsigned short*)alloc((size_t)DI * 64 * 2);
    unsigned short* w_out_b = (unsigned short*)alloc((size_t)DM * DI * 2);
    unsigned short* xz      = (unsigned short*)alloc((size_t)ROWS * 2 * DI * 2);
    unsigned short* xc      = (unsigned short*)alloc((size_t)ROWS * DI * 2);
    float*          xdbl    = (float*)alloc((size_t)ROWS * 96 * 4);
    unsigned short* dt_in   = (unsigned short*)alloc((size_t)ROWS * 64 * 2);
    unsigned short* dt_lin  = (unsigned short*)alloc((size_t)ROWS * DI * 2);
    float*          chP     = (float*)alloc((size_t)BB * NCH * DSTATE * DI * 4);
    float*          chH     = (float*)alloc((size_t)BB * NCH * DSTATE * DI * 4);
    float*          hI      = (float*)alloc((size_t)BB * NCH * DSTATE * DI * 4);
    unsigned short* yb      = (unsigned short*)alloc((size_t)ROWS * DI * 2);

    cvt_weights<<<1024, 256, 0, stream>>>(
        (const float4*)w_in, (const float4*)w_x, (const float4*)w_dt, (const float4*)w_out,
        (ushort4*)w_in_b, (ushort4*)w_x_b, (ushort4*)w_dt_b, (ushort4*)w_out_b,
        (2 * DI * DM) / 4, (96 * DI) / 4, (DI * 64) / 4, (DM * DI) / 4);
    ln_kernel<<<ROWS, 256, 0, stream>>>(hs, ln_g, ln_b, h_bf);
    // in_proj: [4096,1024] x [4096,1024]^T -> xz bf16 [4096,4096]
    gemm_bf16<2, 2, 4, 4, 0><<<dim3(ROWS / 128, (2 * DI) / 128), 256, 0, stream>>>(
        h_bf, w_in_b, nullptr, xz, nullptr, nullptr, ROWS, 2 * DI, DM);
    conv_silu<<<(ROWS * DI) / 256, 256, 0, stream>>>(xz, cw, cb, xc);
    // x_proj: [4096,2048] x [96,2048]^T -> xdbl fp32 [4096,96] (+ dt_in bf16)
    gemm_bf16<4, 1, 1, 6, 1><<<dim3(ROWS / 64, 1), 256, 0, stream>>>(
        xc, w_x_b, xdbl, nullptr, nullptr, dt_in, ROWS, 96, DI);
    // dt_proj: [4096,64] x [2048,64]^T -> dt_lin bf16 [4096,2048]
    gemm_bf16<2, 2, 4, 4, 0><<<dim3(ROWS / 128, DI / 128), 256, 0, stream>>>(
        dt_in, w_dt_b, nullptr, dt_lin, nullptr, nullptr, ROWS, DI, 64);
    scan_pass1<<<(BB * NCH * 32 * 64) / 256, 256, 0, stream>>>(
        dt_lin, dtb, xc, xdbl, A_log, chP, chH);
    scan_combine<<<(BB * DSTATE * DI) / 256, 256, 0, stream>>>(chP, chH, hI);
    scan_pass2<<<(BB * NCH * 32 * 64) / 256, 256, 0, stream>>>(
        dt_lin, dtb, xc, xdbl, A_log, hI, Dp, xz, yb);
    // out_proj: [4096,2048] x [1024,2048]^T + residual -> out fp32 [4096,1024]
    gemm_bf16<2, 2, 4, 4, 2><<<dim3(ROWS / 128, DM / 128), 256, 0, stream>>>(
        yb, w_out_b, out, nullptr, hs, nullptr, ROWS, DM, DI);
}